// Round 1
// baseline (966.320 us; speedup 1.0000x reference)
//
#include <hip/hip_runtime.h>
#include <hip/hip_bf16.h>

// ---------- types ----------
typedef __attribute__((ext_vector_type(8))) short short8;
typedef __attribute__((ext_vector_type(4))) float f32x4;

#define MROWS 4096      // b*l
#define CDIM  1024
#define HEADS 16
#define DHEAD 64
#define NSEQ  1024

// ---------- small device helpers ----------
__device__ inline float softw(const float* __restrict__ w, int idx) {
    // softmax(w/0.01)[idx] over 6 entries
    float m = w[0];
#pragma unroll
    for (int i = 1; i < 6; i++) m = fmaxf(m, w[i]);
    float s = 0.f, v = 0.f;
#pragma unroll
    for (int i = 0; i < 6; i++) {
        float e = __expf((w[i] - m) * 100.0f);
        s += e;
        if (i == idx) v = e;
    }
    return v / s;
}

__device__ inline float gelu_f(float x) {
    return 0.5f * x * (1.0f + erff(x * 0.70710678118654752f));
}

__device__ inline float wred_sum(float v) {
#pragma unroll
    for (int m = 1; m < 64; m <<= 1) v += __shfl_xor(v, m, 64);
    return v;
}

// ---------- prologue: extract x, base mix, zero attn-map accumulator ----------
__global__ __launch_bounds__(256) void mix_base(
    const float* __restrict__ x_list, const float* __restrict__ wvec,
    float* __restrict__ xf, __hip_bfloat16* __restrict__ xb,
    float* __restrict__ xmix, float* __restrict__ am_acc)
{
    int i = blockIdx.x * 256 + threadIdx.x;   // 0 .. 4M-1
    float x0 = x_list[2 * (size_t)i];
    float x1 = x_list[2 * (size_t)i + 1];
    float w0 = softw(wvec, 0), w1 = softw(wvec, 1), w4 = softw(wvec, 4);
    xf[i] = x1;
    xb[i] = __float2bfloat16(x1);
    xmix[i] = w0 * x0 + (w1 + w4) * x1;       // op2 == x == x_list[...,1]
    if (i < 4096) am_acc[i] = 0.f;
}

// ---------- fp32 -> bf16 weight convert ----------
__global__ __launch_bounds__(256) void f2b(const float* __restrict__ in,
                                           __hip_bfloat16* __restrict__ out, int n)
{
    int i = blockIdx.x * 256 + threadIdx.x;
    if (i < n) out[i] = __float2bfloat16(in[i]);
}

// ---------- bf16 MFMA GEMM: C[m,n] = sum_k A[m,k]*W[n,k] (+epilogue) ----------
// EPI: 1=conv(gelu,mix+=w2*), 2=mlp1(gelu->bf16), 3=mlp2(final mix, write f32+bf16),
//      4=proj(+bias+res -> f0), 5=qkv(split-scatter to qf/kf/vf [b,h,n,d])
#define BM 128
#define BN 128
#define BKT 32
#define LDA 40   // 32 + 8 pad (keeps 16B alignment)

template<int EPI>
__global__ __launch_bounds__(256) void gemm_bf16(
    const __hip_bfloat16* __restrict__ A, const __hip_bfloat16* __restrict__ W,
    const float* __restrict__ bias,
    float* __restrict__ f0, float* __restrict__ f1, float* __restrict__ f2,
    __hip_bfloat16* __restrict__ b0,
    const float* __restrict__ wvec, int M, int N, int K)
{
    __shared__ __hip_bfloat16 As[BM * LDA];
    __shared__ __hip_bfloat16 Bs[BN * LDA];
    int t = threadIdx.x;
    int n0 = blockIdx.x * BN, m0 = blockIdx.y * BM;
    int wave = t >> 6, lane = t & 63;
    int wr = wave >> 1, wc = wave & 1;
    int quad = lane >> 4, l16 = lane & 15;

    f32x4 zero = {0.f, 0.f, 0.f, 0.f};
    f32x4 acc[4][4];
#pragma unroll
    for (int i = 0; i < 4; i++)
#pragma unroll
        for (int j = 0; j < 4; j++) acc[i][j] = zero;

    for (int k0 = 0; k0 < K; k0 += BKT) {
        // stage 128x32 bf16 tiles (2 x 16B per thread per matrix)
#pragma unroll
        for (int i = 0; i < 2; i++) {
            int s8 = t + i * 256;
            int r = s8 >> 2, c8 = (s8 & 3) * 8;
            *(short8*)&As[r * LDA + c8] =
                *(const short8*)(A + (size_t)(m0 + r) * K + k0 + c8);
            *(short8*)&Bs[r * LDA + c8] =
                *(const short8*)(W + (size_t)(n0 + r) * K + k0 + c8);
        }
        __syncthreads();
        short8 af[4], bf[4];
#pragma unroll
        for (int i = 0; i < 4; i++) {
            int row = wr * 64 + i * 16 + l16;
            af[i] = *(const short8*)&As[row * LDA + quad * 8];
        }
#pragma unroll
        for (int j = 0; j < 4; j++) {
            int col = wc * 64 + j * 16 + l16;
            bf[j] = *(const short8*)&Bs[col * LDA + quad * 8];
        }
#pragma unroll
        for (int i = 0; i < 4; i++)
#pragma unroll
            for (int j = 0; j < 4; j++)
                acc[i][j] = __builtin_amdgcn_mfma_f32_16x16x32_bf16(
                    af[i], bf[j], acc[i][j], 0, 0, 0);
        __syncthreads();
    }

    float wmx = 0.f;
    if (EPI == 1) wmx = softw(wvec, 2);
    if (EPI == 3) wmx = softw(wvec, 5);

#pragma unroll
    for (int i = 0; i < 4; i++) {
#pragma unroll
        for (int j = 0; j < 4; j++) {
            int col = n0 + wc * 64 + j * 16 + l16;
            float bv = bias[col];
#pragma unroll
            for (int r = 0; r < 4; r++) {
                int row = m0 + wr * 64 + i * 16 + quad * 4 + r;
                float v = acc[i][j][r] + bv;
                size_t idx = (size_t)row * N + col;
                if (EPI == 1) {
                    f0[idx] += wmx * gelu_f(v);               // xmix += w2*op0
                } else if (EPI == 2) {
                    b0[idx] = __float2bfloat16(gelu_f(v));    // mlp hidden
                } else if (EPI == 3) {
                    float tv = f0[idx] + wmx * v;             // final mix
                    f0[idx] = tv;
                    b0[idx] = __float2bfloat16(tv);
                } else if (EPI == 4) {
                    f0[idx] = v + f1[idx];                    // proj + residual
                } else if (EPI == 5) {
                    int portion = col >> 10;                  // 0=q 1=k 2=v
                    int hh = (col >> 6) & 15, dd = col & 63;
                    int bb = row >> 10, nn = row & 1023;
                    float* dst = (portion == 0) ? f0 : (portion == 1) ? f1 : f2;
                    dst[((size_t)(bb * 16 + hh) * NSEQ + nn) * DHEAD + dd] = v;
                }
            }
        }
    }
}

// ---------- ca1: h1 = relu(x @ ca1_w^T + b)  [4096,64], K=1024 ----------
__global__ __launch_bounds__(256) void ca1_kernel(
    const float* __restrict__ xf, const float* __restrict__ w,
    const float* __restrict__ bias, float* __restrict__ h1)
{
    __shared__ float Xs[16 * 65];
    __shared__ float Ws[64 * 65];
    int t = threadIdx.x;
    int m0 = blockIdx.x * 16;
    int row = t >> 4, cg = t & 15;
    float acc[4] = {0.f, 0.f, 0.f, 0.f};
    for (int k0 = 0; k0 < 1024; k0 += 64) {
#pragma unroll
        for (int i = 0; i < 4; i++) {
            int e = t + i * 256; int r = e >> 6, c = e & 63;
            Xs[r * 65 + c] = xf[(size_t)(m0 + r) * 1024 + k0 + c];
        }
#pragma unroll
        for (int i = 0; i < 16; i++) {
            int e = t + i * 256; int r = e >> 6, c = e & 63;
            Ws[r * 65 + c] = w[(size_t)r * 1024 + k0 + c];
        }
        __syncthreads();
        for (int k = 0; k < 64; k++) {
            float xv = Xs[row * 65 + k];
#pragma unroll
            for (int c = 0; c < 4; c++)
                acc[c] += xv * Ws[(cg * 4 + c) * 65 + k];
        }
        __syncthreads();
    }
#pragma unroll
    for (int c = 0; c < 4; c++)
        h1[(size_t)(m0 + row) * 64 + cg * 4 + c] =
            fmaxf(acc[c] + bias[cg * 4 + c], 0.f);
}

// ---------- ca2: xmix += w3 * sigmoid(h1 @ ca2_w^T + b) * x ----------
__global__ __launch_bounds__(256) void ca2_kernel(
    const float* __restrict__ h1, const float* __restrict__ w,
    const float* __restrict__ bias, const float* __restrict__ xf,
    float* __restrict__ xmix, const float* __restrict__ wvec)
{
    __shared__ float Wt[256 * 65];
    __shared__ float hs[16 * 64];
    int t = threadIdx.x;
    int m0 = blockIdx.x * 16, n0 = blockIdx.y * 256;
#pragma unroll
    for (int i = 0; i < 64; i++) {
        int e = t + i * 256; int r = e >> 6, c = e & 63;
        Wt[r * 65 + c] = w[(size_t)(n0 + r) * 64 + c];
    }
#pragma unroll
    for (int i = 0; i < 4; i++) {
        int e = t + i * 256; int r = e >> 6, c = e & 63;
        hs[r * 64 + c] = h1[(size_t)(m0 + r) * 64 + c];
    }
    __syncthreads();
    int n = n0 + t;
    float bv = bias[n];
    float acc[16];
#pragma unroll
    for (int mi = 0; mi < 16; mi++) acc[mi] = bv;
    for (int k = 0; k < 64; k++) {
        float wv = Wt[t * 65 + k];
#pragma unroll
        for (int mi = 0; mi < 16; mi++) acc[mi] += hs[mi * 64 + k] * wv;
    }
    float w3 = softw(wvec, 3);
#pragma unroll
    for (int mi = 0; mi < 16; mi++) {
        size_t idx = (size_t)(m0 + mi) * 1024 + n;
        float sg = 1.f / (1.f + __expf(-acc[mi]));
        xmix[idx] += w3 * sg * xf[idx];
    }
}

// ---------- per-head LayerNorm on q,k (in place) ----------
__global__ __launch_bounds__(256) void prep_attn(
    float* __restrict__ qf, float* __restrict__ kf,
    const float* __restrict__ nqg, const float* __restrict__ nqb,
    const float* __restrict__ nkg, const float* __restrict__ nkb)
{
    int gid = blockIdx.x * 256 + threadIdx.x;
    int wid = gid >> 6, lane = gid & 63;   // wid: 0..65535 rows
    float* qr = qf + (size_t)wid * 64;
    float* kr = kf + (size_t)wid * 64;
    {
        float x = qr[lane];
        float mean = wred_sum(x) * (1.f / 64.f);
        float d = x - mean;
        float var = wred_sum(d * d) * (1.f / 64.f);
        qr[lane] = d * rsqrtf(var + 1e-5f) * nqg[lane] + nqb[lane];
    }
    {
        float x = kr[lane];
        float mean = wred_sum(x) * (1.f / 64.f);
        float d = x - mean;
        float var = wred_sum(d * d) * (1.f / 64.f);
        kr[lane] = d * rsqrtf(var + 1e-5f) * nkg[lane] + nkb[lane];
    }
}

// ---------- fp32 flash attention: out -> ao (bf16, [b,n,c]) ----------
#define ATS 65
__global__ __launch_bounds__(256) void flash_attn(
    const float* __restrict__ qf, const float* __restrict__ kf,
    const float* __restrict__ vf, __hip_bfloat16* __restrict__ ao)
{
    __shared__ float Qs[64 * ATS], Ks[64 * ATS], Vs[64 * ATS], Ps[64 * ATS];
    __shared__ float mro[64], lro[64];
    int bh = blockIdx.x;
    int i0 = blockIdx.y * 64;
    int b = bh >> 4, h = bh & 15;
    const float* qb = qf + (size_t)bh * NSEQ * DHEAD;
    const float* kb = kf + (size_t)bh * NSEQ * DHEAD;
    const float* vb = vf + (size_t)bh * NSEQ * DHEAD;
    int t = threadIdx.x;
    int rg = t >> 4, cg = t & 15;
#pragma unroll
    for (int i = 0; i < 16; i++) {
        int e = t + i * 256; int r = e >> 6, c = e & 63;
        Qs[r * ATS + c] = qb[(size_t)(i0 + r) * 64 + c];
    }
    if (t < 64) { mro[t] = -1e30f; lro[t] = 0.f; }
    float o[4][4];
#pragma unroll
    for (int r = 0; r < 4; r++)
#pragma unroll
        for (int c = 0; c < 4; c++) o[r][c] = 0.f;

    for (int j0 = 0; j0 < NSEQ; j0 += 64) {
#pragma unroll
        for (int i = 0; i < 16; i++) {
            int e = t + i * 256; int r = e >> 6, c = e & 63;
            Ks[r * ATS + c] = kb[(size_t)(j0 + r) * 64 + c];
            Vs[r * ATS + c] = vb[(size_t)(j0 + r) * 64 + c];
        }
        __syncthreads();
        float s[4][4];
#pragma unroll
        for (int r = 0; r < 4; r++)
#pragma unroll
            for (int c = 0; c < 4; c++) s[r][c] = 0.f;
        for (int k = 0; k < 64; k++) {
            float qv[4], kv[4];
#pragma unroll
            for (int r = 0; r < 4; r++) qv[r] = Qs[(rg * 4 + r) * ATS + k];
#pragma unroll
            for (int c = 0; c < 4; c++) kv[c] = Ks[(cg * 4 + c) * ATS + k];
#pragma unroll
            for (int r = 0; r < 4; r++)
#pragma unroll
                for (int c = 0; c < 4; c++) s[r][c] += qv[r] * kv[c];
        }
        float rmax[4], newm[4], alpha[4], rsum[4];
#pragma unroll
        for (int r = 0; r < 4; r++) {
            float mx = -1e30f;
#pragma unroll
            for (int c = 0; c < 4; c++) { s[r][c] *= 0.125f; mx = fmaxf(mx, s[r][c]); }
#pragma unroll
            for (int mm = 1; mm < 16; mm <<= 1) mx = fmaxf(mx, __shfl_xor(mx, mm, 64));
            rmax[r] = mx;
        }
#pragma unroll
        for (int r = 0; r < 4; r++) {
            float om = mro[rg * 4 + r];                // 16-lane group in lockstep: safe
            newm[r] = fmaxf(om, rmax[r]);
            alpha[r] = __expf(om - newm[r]);
        }
#pragma unroll
        for (int r = 0; r < 4; r++) {
            float ss = 0.f;
#pragma unroll
            for (int c = 0; c < 4; c++) {
                float p = __expf(s[r][c] - newm[r]);
                Ps[(rg * 4 + r) * ATS + cg * 4 + c] = p;
                ss += p;
            }
#pragma unroll
            for (int mm = 1; mm < 16; mm <<= 1) ss += __shfl_xor(ss, mm, 64);
            rsum[r] = ss;
        }
        if (cg == 0) {
#pragma unroll
            for (int r = 0; r < 4; r++) {
                mro[rg * 4 + r] = newm[r];
                lro[rg * 4 + r] = lro[rg * 4 + r] * alpha[r] + rsum[r];
            }
        }
#pragma unroll
        for (int r = 0; r < 4; r++)
#pragma unroll
            for (int c = 0; c < 4; c++) o[r][c] *= alpha[r];
        __syncthreads();   // Ps visible
        for (int j = 0; j < 64; j++) {
            float pv[4], vv[4];
#pragma unroll
            for (int r = 0; r < 4; r++) pv[r] = Ps[(rg * 4 + r) * ATS + j];
#pragma unroll
            for (int c = 0; c < 4; c++) vv[c] = Vs[j * ATS + cg * 4 + c];
#pragma unroll
            for (int r = 0; r < 4; r++)
#pragma unroll
                for (int c = 0; c < 4; c++) o[r][c] += pv[r] * vv[c];
        }
        __syncthreads();   // done with Ks/Vs/Ps
    }
#pragma unroll
    for (int r = 0; r < 4; r++) {
        float inv = 1.f / lro[rg * 4 + r];
#pragma unroll
        for (int c = 0; c < 4; c++) {
            size_t idx = ((size_t)b * NSEQ + i0 + rg * 4 + r) * CDIM + h * 64 + cg * 4 + c;
            ao[idx] = __float2bfloat16(o[r][c] * inv);
        }
    }
}

// ---------- attn_map: mean over heads of attn[:,0,1:] ----------
__global__ __launch_bounds__(256) void attn_map_acc(
    const float* __restrict__ qf, const float* __restrict__ kf,
    float* __restrict__ am)
{
    __shared__ float q0[64];
    __shared__ float red[256];
    int bh = blockIdx.x, t = threadIdx.x;
    const float* qr = qf + (size_t)bh * NSEQ * DHEAD;   // row 0
    const float* kb = kf + (size_t)bh * NSEQ * DHEAD;
    if (t < 64) q0[t] = qr[t];
    __syncthreads();
    float s[4];
    float mx = -1e30f;
#pragma unroll
    for (int ji = 0; ji < 4; ji++) {
        int j = ji * 256 + t;
        float a = 0.f;
        for (int k = 0; k < 64; k++) a += q0[k] * kb[(size_t)j * 64 + k];
        a *= 0.125f;
        s[ji] = a;
        mx = fmaxf(mx, a);
    }
    red[t] = mx; __syncthreads();
    for (int st = 128; st > 0; st >>= 1) {
        if (t < st) red[t] = fmaxf(red[t], red[t + st]);
        __syncthreads();
    }
    float M = red[0]; __syncthreads();
    float sum = 0.f;
#pragma unroll
    for (int ji = 0; ji < 4; ji++) { s[ji] = __expf(s[ji] - M); sum += s[ji]; }
    red[t] = sum; __syncthreads();
    for (int st = 128; st > 0; st >>= 1) {
        if (t < st) red[t] += red[t + st];
        __syncthreads();
    }
    float inv = 1.f / red[0];
    int b = bh >> 4;
#pragma unroll
    for (int ji = 0; ji < 4; ji++) {
        int j = ji * 256 + t;
        if (j > 0) atomicAdd(&am[b * 1024 + j], s[ji] * inv * (1.f / 16.f));
    }
}

__global__ __launch_bounds__(256) void attn_map_out(
    const float* __restrict__ am, float* __restrict__ out1)
{
    int i = blockIdx.x * 256 + threadIdx.x;
    if (i < 4 * 1023) {
        int b = i / 1023;
        int j = i - b * 1023 + 1;
        out1[i] = am[b * 1024 + j];
    }
}

// ---------- launch ----------
extern "C" void kernel_launch(void* const* d_in, const int* in_sizes, int n_in,
                              void* d_out, int out_size, void* d_ws, size_t ws_size,
                              hipStream_t stream)
{
    const float* x_list = (const float*)d_in[0];
    const float* wvec   = (const float*)d_in[1];
    const float* qkv_w  = (const float*)d_in[2];
    const float* qkv_b  = (const float*)d_in[3];
    const float* proj_w = (const float*)d_in[4];
    const float* proj_b = (const float*)d_in[5];
    const float* nq_g   = (const float*)d_in[6];
    const float* nq_b   = (const float*)d_in[7];
    const float* nk_g   = (const float*)d_in[8];
    const float* nk_b   = (const float*)d_in[9];
    const float* conv_w = (const float*)d_in[10];
    const float* conv_b = (const float*)d_in[11];
    const float* ca1_w  = (const float*)d_in[12];
    const float* ca1_b  = (const float*)d_in[13];
    const float* ca2_w  = (const float*)d_in[14];
    const float* ca2_b  = (const float*)d_in[15];
    const float* mlp1_w = (const float*)d_in[16];
    const float* mlp1_b = (const float*)d_in[17];
    const float* mlp2_w = (const float*)d_in[18];
    const float* mlp2_b = (const float*)d_in[19];

    float* out0 = (float*)d_out;
    float* out1 = out0 + (size_t)4 * 1024 * 1024;

    char* ws = (char*)d_ws;
    size_t off = 0;
    auto alloc = [&](size_t bytes) -> char* {
        char* p = ws + off;
        off += (bytes + 255) & ~(size_t)255;
        return p;
    };
    float*          xf     = (float*)alloc((size_t)MROWS * CDIM * 4);
    __hip_bfloat16* xb     = (__hip_bfloat16*)alloc((size_t)MROWS * CDIM * 2);
    float*          xmix   = (float*)alloc((size_t)MROWS * CDIM * 4);
    __hip_bfloat16* xmixb  = (__hip_bfloat16*)alloc((size_t)MROWS * CDIM * 2);
    float*          h1     = (float*)alloc((size_t)MROWS * 64 * 4);
    __hip_bfloat16* hb     = (__hip_bfloat16*)alloc((size_t)MROWS * 4096 * 2);
    float*          qfb    = (float*)alloc((size_t)MROWS * CDIM * 4);
    float*          kfb    = (float*)alloc((size_t)MROWS * CDIM * 4);
    float*          vfb    = (float*)alloc((size_t)MROWS * CDIM * 4);
    __hip_bfloat16* aob    = (__hip_bfloat16*)alloc((size_t)MROWS * CDIM * 2);
    float*          amacc  = (float*)alloc(4096 * 4);
    __hip_bfloat16* convwb = (__hip_bfloat16*)alloc((size_t)1048576 * 2);
    __hip_bfloat16* qkvwb  = (__hip_bfloat16*)alloc((size_t)3145728 * 2);
    __hip_bfloat16* projwb = (__hip_bfloat16*)alloc((size_t)1048576 * 2);
    __hip_bfloat16* mlp1wb = (__hip_bfloat16*)alloc((size_t)4194304 * 2);
    __hip_bfloat16* mlp2wb = (__hip_bfloat16*)alloc((size_t)4194304 * 2);

    // weight converts
    f2b<<<4096, 256, 0, stream>>>(conv_w, convwb, 1048576);
    f2b<<<12288, 256, 0, stream>>>(qkv_w, qkvwb, 3145728);
    f2b<<<4096, 256, 0, stream>>>(proj_w, projwb, 1048576);
    f2b<<<16384, 256, 0, stream>>>(mlp1_w, mlp1wb, 4194304);
    f2b<<<16384, 256, 0, stream>>>(mlp2_w, mlp2wb, 4194304);

    // prologue
    mix_base<<<16384, 256, 0, stream>>>(x_list, wvec, xf, xb, xmix, amacc);

    // op0: conv (gelu) -> xmix += w2*...
    gemm_bf16<1><<<dim3(8, 32), 256, 0, stream>>>(
        xb, convwb, conv_b, xmix, nullptr, nullptr, nullptr, wvec, MROWS, 1024, 1024);

    // op1: channel attention
    ca1_kernel<<<256, 256, 0, stream>>>(xf, ca1_w, ca1_b, h1);
    ca2_kernel<<<dim3(256, 4), 256, 0, stream>>>(h1, ca2_w, ca2_b, xf, xmix, wvec);

    // op3: MLP
    gemm_bf16<2><<<dim3(32, 32), 256, 0, stream>>>(
        xb, mlp1wb, mlp1_b, nullptr, nullptr, nullptr, hb, wvec, MROWS, 4096, 1024);
    gemm_bf16<3><<<dim3(8, 32), 256, 0, stream>>>(
        hb, mlp2wb, mlp2_b, xmix, nullptr, nullptr, xmixb, wvec, MROWS, 1024, 4096);

    // qkv (split-scatter into [b,h,n,d])
    gemm_bf16<5><<<dim3(24, 32), 256, 0, stream>>>(
        xmixb, qkvwb, qkv_b, qfb, kfb, vfb, nullptr, wvec, MROWS, 3072, 1024);

    // per-head LN on q,k
    prep_attn<<<16384, 256, 0, stream>>>(qfb, kfb, nq_g, nq_b, nk_g, nk_b);

    // attention
    flash_attn<<<dim3(64, 16), 256, 0, stream>>>(qfb, kfb, vfb, aob);

    // attn_map
    attn_map_acc<<<64, 256, 0, stream>>>(qfb, kfb, amacc);
    attn_map_out<<<16, 256, 0, stream>>>(amacc, out1);

    // projection + residual
    gemm_bf16<4><<<dim3(8, 32), 256, 0, stream>>>(
        aob, projwb, proj_b, out0, xmix, nullptr, nullptr, wvec, MROWS, 1024, 1024);
}

// Round 2
// 646.294 us; speedup vs baseline: 1.4952x; 1.4952x over previous
//
#include <hip/hip_runtime.h>
#include <hip/hip_bf16.h>

// ---------- types ----------
typedef __attribute__((ext_vector_type(8))) short short8;
typedef __attribute__((ext_vector_type(4))) float f32x4;

#define MROWS 4096      // b*l
#define CDIM  1024
#define HEADS 16
#define DHEAD 64
#define NSEQ  1024

// ---------- small device helpers ----------
__device__ inline float softw(const float* __restrict__ w, int idx) {
    // softmax(w/0.01)[idx] over 6 entries
    float m = w[0];
#pragma unroll
    for (int i = 1; i < 6; i++) m = fmaxf(m, w[i]);
    float s = 0.f, v = 0.f;
#pragma unroll
    for (int i = 0; i < 6; i++) {
        float e = __expf((w[i] - m) * 100.0f);
        s += e;
        if (i == idx) v = e;
    }
    return v / s;
}

__device__ inline float gelu_f(float x) {
    return 0.5f * x * (1.0f + erff(x * 0.70710678118654752f));
}

__device__ inline float wred_sum(float v) {
#pragma unroll
    for (int m = 1; m < 64; m <<= 1) v += __shfl_xor(v, m, 64);
    return v;
}

// ---------- prologue: extract x, base mix, zero attn-map accumulator ----------
__global__ __launch_bounds__(256) void mix_base(
    const float* __restrict__ x_list, const float* __restrict__ wvec,
    float* __restrict__ xf, __hip_bfloat16* __restrict__ xb,
    float* __restrict__ xmix, float* __restrict__ am_acc)
{
    int i = blockIdx.x * 256 + threadIdx.x;   // 0 .. 4M-1
    float x0 = x_list[2 * (size_t)i];
    float x1 = x_list[2 * (size_t)i + 1];
    float w0 = softw(wvec, 0), w1 = softw(wvec, 1), w4 = softw(wvec, 4);
    xf[i] = x1;
    xb[i] = __float2bfloat16(x1);
    xmix[i] = w0 * x0 + (w1 + w4) * x1;       // op2 == x == x_list[...,1]
    if (i < 4096) am_acc[i] = 0.f;
}

// ---------- fp32 -> bf16 weight convert ----------
__global__ __launch_bounds__(256) void f2b(const float* __restrict__ in,
                                           __hip_bfloat16* __restrict__ out, int n)
{
    int i = blockIdx.x * 256 + threadIdx.x;
    if (i < n) out[i] = __float2bfloat16(in[i]);
}

// ---------- bf16 MFMA GEMM: C[m,n] = sum_k A[m,k]*W[n,k] (+epilogue) ----------
// EPI: 1=conv(gelu,mix+=w2*), 2=mlp1(gelu->bf16), 3=mlp2(final mix, write f32+bf16),
//      4=proj(+bias+res -> f0), 5=qkv(q,k fp32 [b,h,n,d]; v bf16 V^T [b,h,d,n])
#define BM 128
#define BN 128
#define BKT 32
#define LDA 40   // 32 + 8 pad (keeps 16B alignment)

template<int EPI>
__global__ __launch_bounds__(256) void gemm_bf16(
    const __hip_bfloat16* __restrict__ A, const __hip_bfloat16* __restrict__ W,
    const float* __restrict__ bias,
    float* __restrict__ f0, float* __restrict__ f1, float* __restrict__ f2,
    __hip_bfloat16* __restrict__ b0,
    const float* __restrict__ wvec, int M, int N, int K)
{
    __shared__ __hip_bfloat16 As[BM * LDA];
    __shared__ __hip_bfloat16 Bs[BN * LDA];
    int t = threadIdx.x;
    int n0 = blockIdx.x * BN, m0 = blockIdx.y * BM;
    int wave = t >> 6, lane = t & 63;
    int wr = wave >> 1, wc = wave & 1;
    int quad = lane >> 4, l16 = lane & 15;

    f32x4 zero = {0.f, 0.f, 0.f, 0.f};
    f32x4 acc[4][4];
#pragma unroll
    for (int i = 0; i < 4; i++)
#pragma unroll
        for (int j = 0; j < 4; j++) acc[i][j] = zero;

    for (int k0 = 0; k0 < K; k0 += BKT) {
        // stage 128x32 bf16 tiles (2 x 16B per thread per matrix)
#pragma unroll
        for (int i = 0; i < 2; i++) {
            int s8 = t + i * 256;
            int r = s8 >> 2, c8 = (s8 & 3) * 8;
            *(short8*)&As[r * LDA + c8] =
                *(const short8*)(A + (size_t)(m0 + r) * K + k0 + c8);
            *(short8*)&Bs[r * LDA + c8] =
                *(const short8*)(W + (size_t)(n0 + r) * K + k0 + c8);
        }
        __syncthreads();
        short8 af[4], bf[4];
#pragma unroll
        for (int i = 0; i < 4; i++) {
            int row = wr * 64 + i * 16 + l16;
            af[i] = *(const short8*)&As[row * LDA + quad * 8];
        }
#pragma unroll
        for (int j = 0; j < 4; j++) {
            int col = wc * 64 + j * 16 + l16;
            bf[j] = *(const short8*)&Bs[col * LDA + quad * 8];
        }
#pragma unroll
        for (int i = 0; i < 4; i++)
#pragma unroll
            for (int j = 0; j < 4; j++)
                acc[i][j] = __builtin_amdgcn_mfma_f32_16x16x32_bf16(
                    af[i], bf[j], acc[i][j], 0, 0, 0);
        __syncthreads();
    }

    float wmx = 0.f;
    if (EPI == 1) wmx = softw(wvec, 2);
    if (EPI == 3) wmx = softw(wvec, 5);

#pragma unroll
    for (int i = 0; i < 4; i++) {
#pragma unroll
        for (int j = 0; j < 4; j++) {
            int col = n0 + wc * 64 + j * 16 + l16;
            float bv = bias[col];
#pragma unroll
            for (int r = 0; r < 4; r++) {
                int row = m0 + wr * 64 + i * 16 + quad * 4 + r;
                float v = acc[i][j][r] + bv;
                size_t idx = (size_t)row * N + col;
                if (EPI == 1) {
                    f0[idx] += wmx * gelu_f(v);               // xmix += w2*op0
                } else if (EPI == 2) {
                    b0[idx] = __float2bfloat16(gelu_f(v));    // mlp hidden
                } else if (EPI == 3) {
                    float tv = f0[idx] + wmx * v;             // final mix
                    f0[idx] = tv;
                    b0[idx] = __float2bfloat16(tv);
                } else if (EPI == 4) {
                    f0[idx] = v + f1[idx];                    // proj + residual
                } else if (EPI == 5) {
                    int portion = col >> 10;                  // 0=q 1=k 2=v
                    int hh = (col >> 6) & 15, dd = col & 63;
                    int bb = row >> 10, nn = row & 1023;
                    if (portion == 2) {
                        // V^T bf16: [b,h,d,n]
                        b0[((size_t)(bb * 16 + hh) * DHEAD + dd) * NSEQ + nn] =
                            __float2bfloat16(v);
                    } else {
                        float* dst = (portion == 0) ? f0 : f1;
                        dst[((size_t)(bb * 16 + hh) * NSEQ + nn) * DHEAD + dd] = v;
                    }
                }
            }
        }
    }
}

// ---------- ca1: h1 = relu(x @ ca1_w^T + b)  [4096,64], K=1024 ----------
__global__ __launch_bounds__(256) void ca1_kernel(
    const float* __restrict__ xf, const float* __restrict__ w,
    const float* __restrict__ bias, float* __restrict__ h1)
{
    __shared__ float Xs[16 * 65];
    __shared__ float Ws[64 * 65];
    int t = threadIdx.x;
    int m0 = blockIdx.x * 16;
    int row = t >> 4, cg = t & 15;
    float acc[4] = {0.f, 0.f, 0.f, 0.f};
    for (int k0 = 0; k0 < 1024; k0 += 64) {
#pragma unroll
        for (int i = 0; i < 4; i++) {
            int e = t + i * 256; int r = e >> 6, c = e & 63;
            Xs[r * 65 + c] = xf[(size_t)(m0 + r) * 1024 + k0 + c];
        }
#pragma unroll
        for (int i = 0; i < 16; i++) {
            int e = t + i * 256; int r = e >> 6, c = e & 63;
            Ws[r * 65 + c] = w[(size_t)r * 1024 + k0 + c];
        }
        __syncthreads();
        for (int k = 0; k < 64; k++) {
            float xv = Xs[row * 65 + k];
#pragma unroll
            for (int c = 0; c < 4; c++)
                acc[c] += xv * Ws[(cg * 4 + c) * 65 + k];
        }
        __syncthreads();
    }
#pragma unroll
    for (int c = 0; c < 4; c++)
        h1[(size_t)(m0 + row) * 64 + cg * 4 + c] =
            fmaxf(acc[c] + bias[cg * 4 + c], 0.f);
}

// ---------- ca2: xmix += w3 * sigmoid(h1 @ ca2_w^T + b) * x ----------
__global__ __launch_bounds__(256) void ca2_kernel(
    const float* __restrict__ h1, const float* __restrict__ w,
    const float* __restrict__ bias, const float* __restrict__ xf,
    float* __restrict__ xmix, const float* __restrict__ wvec)
{
    __shared__ float Wt[256 * 65];
    __shared__ float hs[16 * 64];
    int t = threadIdx.x;
    int m0 = blockIdx.x * 16, n0 = blockIdx.y * 256;
#pragma unroll
    for (int i = 0; i < 64; i++) {
        int e = t + i * 256; int r = e >> 6, c = e & 63;
        Wt[r * 65 + c] = w[(size_t)(n0 + r) * 64 + c];
    }
#pragma unroll
    for (int i = 0; i < 4; i++) {
        int e = t + i * 256; int r = e >> 6, c = e & 63;
        hs[r * 64 + c] = h1[(size_t)(m0 + r) * 64 + c];
    }
    __syncthreads();
    int n = n0 + t;
    float bv = bias[n];
    float acc[16];
#pragma unroll
    for (int mi = 0; mi < 16; mi++) acc[mi] = bv;
    for (int k = 0; k < 64; k++) {
        float wv = Wt[t * 65 + k];
#pragma unroll
        for (int mi = 0; mi < 16; mi++) acc[mi] += hs[mi * 64 + k] * wv;
    }
    float w3 = softw(wvec, 3);
#pragma unroll
    for (int mi = 0; mi < 16; mi++) {
        size_t idx = (size_t)(m0 + mi) * 1024 + n;
        float sg = 1.f / (1.f + __expf(-acc[mi]));
        xmix[idx] += w3 * sg * xf[idx];
    }
}

// ---------- per-head LayerNorm on q,k: fp32 in -> bf16 out ----------
__global__ __launch_bounds__(256) void prep_attn(
    const float* __restrict__ qf, const float* __restrict__ kf,
    __hip_bfloat16* __restrict__ qo, __hip_bfloat16* __restrict__ ko,
    const float* __restrict__ nqg, const float* __restrict__ nqb,
    const float* __restrict__ nkg, const float* __restrict__ nkb)
{
    int gid = blockIdx.x * 256 + threadIdx.x;
    int wid = gid >> 6, lane = gid & 63;   // wid: 0..65535 rows
    {
        float x = qf[(size_t)wid * 64 + lane];
        float mean = wred_sum(x) * (1.f / 64.f);
        float d = x - mean;
        float var = wred_sum(d * d) * (1.f / 64.f);
        qo[(size_t)wid * 64 + lane] =
            __float2bfloat16(d * rsqrtf(var + 1e-5f) * nqg[lane] + nqb[lane]);
    }
    {
        float x = kf[(size_t)wid * 64 + lane];
        float mean = wred_sum(x) * (1.f / 64.f);
        float d = x - mean;
        float var = wred_sum(d * d) * (1.f / 64.f);
        ko[(size_t)wid * 64 + lane] =
            __float2bfloat16(d * rsqrtf(var + 1e-5f) * nkg[lane] + nkb[lane]);
    }
}

// ---------- MFMA flash attention ----------
// grid (64 bh, 8 i-tiles), block 256 (4 waves). Wave owns 32 q-rows.
// Q/K bf16 [b,h,n,d]; V^T bf16 [b,h,d,n]; out ao bf16 [b,n,c].
// K/V fragments read direct from global (L2-resident per bh on one XCD).
// P round-trips through wave-private LDS (no barriers in kernel).
#define PSTR 72   // bf16 stride: 144 B, 16B-aligned, 2-way banks
__global__ __launch_bounds__(256) void flash_mfma(
    const __hip_bfloat16* __restrict__ qb, const __hip_bfloat16* __restrict__ kb,
    const __hip_bfloat16* __restrict__ vt, __hip_bfloat16* __restrict__ ao)
{
    __shared__ __hip_bfloat16 Plds[4][32 * PSTR];
    int bh = blockIdx.x;
    int i0 = blockIdx.y * 128;
    int b = bh >> 4, h = bh & 15;
    int t = threadIdx.x, wave = t >> 6, lane = t & 63;
    int l16 = lane & 15, quad = lane >> 4;
    const __hip_bfloat16* qbase = qb + (size_t)bh * NSEQ * DHEAD;
    const __hip_bfloat16* kbase = kb + (size_t)bh * NSEQ * DHEAD;
    const __hip_bfloat16* vbase = vt + (size_t)bh * DHEAD * NSEQ;
    __hip_bfloat16* pw = Plds[wave];
    int qrow0 = i0 + wave * 32;

    // Q fragments, held for the whole kernel
    short8 aq[2][2];
#pragma unroll
    for (int ri = 0; ri < 2; ri++)
#pragma unroll
        for (int ks = 0; ks < 2; ks++)
            aq[ri][ks] = *(const short8*)(qbase +
                (size_t)(qrow0 + ri * 16 + l16) * DHEAD + ks * 32 + quad * 8);

    f32x4 zero = {0.f, 0.f, 0.f, 0.f};
    f32x4 o[2][4];
    float mrow[2][4], lrow[2][4];
#pragma unroll
    for (int ri = 0; ri < 2; ri++) {
#pragma unroll
        for (int nt = 0; nt < 4; nt++) o[ri][nt] = zero;
#pragma unroll
        for (int rr = 0; rr < 4; rr++) { mrow[ri][rr] = -1e30f; lrow[ri][rr] = 0.f; }
    }

    for (int j0 = 0; j0 < NSEQ; j0 += 64) {
        // K fragments: B[n=key][k=d]
        short8 bk[4][2];
#pragma unroll
        for (int jt = 0; jt < 4; jt++)
#pragma unroll
            for (int ks = 0; ks < 2; ks++)
                bk[jt][ks] = *(const short8*)(kbase +
                    (size_t)(j0 + jt * 16 + l16) * DHEAD + ks * 32 + quad * 8);
        // V^T fragments: B[n=d][k=key]
        short8 bv[4][2];
#pragma unroll
        for (int nt = 0; nt < 4; nt++)
#pragma unroll
            for (int ks = 0; ks < 2; ks++)
                bv[nt][ks] = *(const short8*)(vbase +
                    (size_t)(nt * 16 + l16) * NSEQ + j0 + ks * 32 + quad * 8);

#pragma unroll
        for (int ri = 0; ri < 2; ri++) {
            f32x4 s[4];
#pragma unroll
            for (int jt = 0; jt < 4; jt++) s[jt] = zero;
#pragma unroll
            for (int jt = 0; jt < 4; jt++)
#pragma unroll
                for (int ks = 0; ks < 2; ks++)
                    s[jt] = __builtin_amdgcn_mfma_f32_16x16x32_bf16(
                        aq[ri][ks], bk[jt][ks], s[jt], 0, 0, 0);
            // online softmax, row = quad*4+rr (C-layout), col = jt*16+l16
#pragma unroll
            for (int rr = 0; rr < 4; rr++) {
                float mx = -1e30f;
#pragma unroll
                for (int jt = 0; jt < 4; jt++) {
                    s[jt][rr] *= 0.125f;
                    mx = fmaxf(mx, s[jt][rr]);
                }
#pragma unroll
                for (int mk = 1; mk < 16; mk <<= 1) mx = fmaxf(mx, __shfl_xor(mx, mk, 64));
                float om = mrow[ri][rr];
                float nm = fmaxf(om, mx);
                float al = __expf(om - nm);
                mrow[ri][rr] = nm;
                float ss = 0.f;
#pragma unroll
                for (int jt = 0; jt < 4; jt++) {
                    float p = __expf(s[jt][rr] - nm);
                    pw[(ri * 16 + quad * 4 + rr) * PSTR + jt * 16 + l16] =
                        __float2bfloat16(p);
                    ss += p;
                }
#pragma unroll
                for (int mk = 1; mk < 16; mk <<= 1) ss += __shfl_xor(ss, mk, 64);
                lrow[ri][rr] = lrow[ri][rr] * al + ss;
#pragma unroll
                for (int nt = 0; nt < 4; nt++) o[ri][nt][rr] *= al;
            }
        }
        // PV: A = P from wave-private LDS (compiler inserts lgkmcnt wait)
#pragma unroll
        for (int ri = 0; ri < 2; ri++) {
            short8 ap[2];
#pragma unroll
            for (int ks = 0; ks < 2; ks++)
                ap[ks] = *(const short8*)&pw[(ri * 16 + l16) * PSTR + ks * 32 + quad * 8];
#pragma unroll
            for (int nt = 0; nt < 4; nt++)
#pragma unroll
                for (int ks = 0; ks < 2; ks++)
                    o[ri][nt] = __builtin_amdgcn_mfma_f32_16x16x32_bf16(
                        ap[ks], bv[nt][ks], o[ri][nt], 0, 0, 0);
        }
    }

#pragma unroll
    for (int ri = 0; ri < 2; ri++)
#pragma unroll
        for (int rr = 0; rr < 4; rr++) {
            float inv = 1.f / lrow[ri][rr];
            int row = qrow0 + ri * 16 + quad * 4 + rr;
#pragma unroll
            for (int nt = 0; nt < 4; nt++)
                ao[((size_t)b * NSEQ + row) * CDIM + h * 64 + nt * 16 + l16] =
                    __float2bfloat16(o[ri][nt][rr] * inv);
        }
}

// ---------- attn_map: mean over heads of attn[:,0,1:] ----------
__global__ __launch_bounds__(256) void attn_map_acc(
    const __hip_bfloat16* __restrict__ qf, const __hip_bfloat16* __restrict__ kf,
    float* __restrict__ am)
{
    __shared__ float q0[64];
    __shared__ float red[256];
    int bh = blockIdx.x, t = threadIdx.x;
    const __hip_bfloat16* qr = qf + (size_t)bh * NSEQ * DHEAD;   // row 0
    const __hip_bfloat16* kb = kf + (size_t)bh * NSEQ * DHEAD;
    if (t < 64) q0[t] = __bfloat162float(qr[t]);
    __syncthreads();
    float s[4];
    float mx = -1e30f;
#pragma unroll
    for (int ji = 0; ji < 4; ji++) {
        int j = ji * 256 + t;
        float a = 0.f;
        for (int k = 0; k < 64; k++) a += q0[k] * __bfloat162float(kb[(size_t)j * 64 + k]);
        a *= 0.125f;
        s[ji] = a;
        mx = fmaxf(mx, a);
    }
    red[t] = mx; __syncthreads();
    for (int st = 128; st > 0; st >>= 1) {
        if (t < st) red[t] = fmaxf(red[t], red[t + st]);
        __syncthreads();
    }
    float M = red[0]; __syncthreads();
    float sum = 0.f;
#pragma unroll
    for (int ji = 0; ji < 4; ji++) { s[ji] = __expf(s[ji] - M); sum += s[ji]; }
    red[t] = sum; __syncthreads();
    for (int st = 128; st > 0; st >>= 1) {
        if (t < st) red[t] += red[t + st];
        __syncthreads();
    }
    float inv = 1.f / red[0];
    int b = bh >> 4;
#pragma unroll
    for (int ji = 0; ji < 4; ji++) {
        int j = ji * 256 + t;
        if (j > 0) atomicAdd(&am[b * 1024 + j], s[ji] * inv * (1.f / 16.f));
    }
}

__global__ __launch_bounds__(256) void attn_map_out(
    const float* __restrict__ am, float* __restrict__ out1)
{
    int i = blockIdx.x * 256 + threadIdx.x;
    if (i < 4 * 1023) {
        int b = i / 1023;
        int j = i - b * 1023 + 1;
        out1[i] = am[b * 1024 + j];
    }
}

// ---------- launch ----------
extern "C" void kernel_launch(void* const* d_in, const int* in_sizes, int n_in,
                              void* d_out, int out_size, void* d_ws, size_t ws_size,
                              hipStream_t stream)
{
    const float* x_list = (const float*)d_in[0];
    const float* wvec   = (const float*)d_in[1];
    const float* qkv_w  = (const float*)d_in[2];
    const float* qkv_b  = (const float*)d_in[3];
    const float* proj_w = (const float*)d_in[4];
    const float* proj_b = (const float*)d_in[5];
    const float* nq_g   = (const float*)d_in[6];
    const float* nq_b   = (const float*)d_in[7];
    const float* nk_g   = (const float*)d_in[8];
    const float* nk_b   = (const float*)d_in[9];
    const float* conv_w = (const float*)d_in[10];
    const float* conv_b = (const float*)d_in[11];
    const float* ca1_w  = (const float*)d_in[12];
    const float* ca1_b  = (const float*)d_in[13];
    const float* ca2_w  = (const float*)d_in[14];
    const float* ca2_b  = (const float*)d_in[15];
    const float* mlp1_w = (const float*)d_in[16];
    const float* mlp1_b = (const float*)d_in[17];
    const float* mlp2_w = (const float*)d_in[18];
    const float* mlp2_b = (const float*)d_in[19];

    float* out0 = (float*)d_out;
    float* out1 = out0 + (size_t)4 * 1024 * 1024;

    char* ws = (char*)d_ws;
    size_t off = 0;
    auto alloc = [&](size_t bytes) -> char* {
        char* p = ws + off;
        off += (bytes + 255) & ~(size_t)255;
        return p;
    };
    float*          xf     = (float*)alloc((size_t)MROWS * CDIM * 4);
    __hip_bfloat16* xb     = (__hip_bfloat16*)alloc((size_t)MROWS * CDIM * 2);
    float*          xmix   = (float*)alloc((size_t)MROWS * CDIM * 4);
    __hip_bfloat16* xmixb  = (__hip_bfloat16*)alloc((size_t)MROWS * CDIM * 2);
    float*          h1     = (float*)alloc((size_t)MROWS * 64 * 4);
    __hip_bfloat16* hb     = (__hip_bfloat16*)alloc((size_t)MROWS * 4096 * 2);
    float*          qfb    = (float*)alloc((size_t)MROWS * CDIM * 4);
    float*          kfb    = (float*)alloc((size_t)MROWS * CDIM * 4);
    __hip_bfloat16* qbb    = (__hip_bfloat16*)alloc((size_t)MROWS * CDIM * 2);
    __hip_bfloat16* kbb    = (__hip_bfloat16*)alloc((size_t)MROWS * CDIM * 2);
    __hip_bfloat16* vtb    = (__hip_bfloat16*)alloc((size_t)MROWS * CDIM * 2);
    __hip_bfloat16* aob    = (__hip_bfloat16*)alloc((size_t)MROWS * CDIM * 2);
    float*          amacc  = (float*)alloc(4096 * 4);
    __hip_bfloat16* convwb = (__hip_bfloat16*)alloc((size_t)1048576 * 2);
    __hip_bfloat16* qkvwb  = (__hip_bfloat16*)alloc((size_t)3145728 * 2);
    __hip_bfloat16* projwb = (__hip_bfloat16*)alloc((size_t)1048576 * 2);
    __hip_bfloat16* mlp1wb = (__hip_bfloat16*)alloc((size_t)4194304 * 2);
    __hip_bfloat16* mlp2wb = (__hip_bfloat16*)alloc((size_t)4194304 * 2);

    // weight converts
    f2b<<<4096, 256, 0, stream>>>(conv_w, convwb, 1048576);
    f2b<<<12288, 256, 0, stream>>>(qkv_w, qkvwb, 3145728);
    f2b<<<4096, 256, 0, stream>>>(proj_w, projwb, 1048576);
    f2b<<<16384, 256, 0, stream>>>(mlp1_w, mlp1wb, 4194304);
    f2b<<<16384, 256, 0, stream>>>(mlp2_w, mlp2wb, 4194304);

    // prologue
    mix_base<<<16384, 256, 0, stream>>>(x_list, wvec, xf, xb, xmix, amacc);

    // op0: conv (gelu) -> xmix += w2*...
    gemm_bf16<1><<<dim3(8, 32), 256, 0, stream>>>(
        xb, convwb, conv_b, xmix, nullptr, nullptr, nullptr, wvec, MROWS, 1024, 1024);

    // op1: channel attention
    ca1_kernel<<<256, 256, 0, stream>>>(xf, ca1_w, ca1_b, h1);
    ca2_kernel<<<dim3(256, 4), 256, 0, stream>>>(h1, ca2_w, ca2_b, xf, xmix, wvec);

    // op3: MLP
    gemm_bf16<2><<<dim3(32, 32), 256, 0, stream>>>(
        xb, mlp1wb, mlp1_b, nullptr, nullptr, nullptr, hb, wvec, MROWS, 4096, 1024);
    gemm_bf16<3><<<dim3(8, 32), 256, 0, stream>>>(
        hb, mlp2wb, mlp2_b, xmix, nullptr, nullptr, xmixb, wvec, MROWS, 1024, 4096);

    // qkv (q,k fp32 [b,h,n,d]; v -> V^T bf16 [b,h,d,n])
    gemm_bf16<5><<<dim3(24, 32), 256, 0, stream>>>(
        xmixb, qkvwb, qkv_b, qfb, kfb, nullptr, vtb, wvec, MROWS, 3072, 1024);

    // per-head LN on q,k -> bf16
    prep_attn<<<16384, 256, 0, stream>>>(qfb, kfb, qbb, kbb, nq_g, nq_b, nk_g, nk_b);

    // attention (MFMA)
    flash_mfma<<<dim3(64, 8), 256, 0, stream>>>(qbb, kbb, vtb, aob);

    // attn_map
    attn_map_acc<<<64, 256, 0, stream>>>(qbb, kbb, amacc);
    attn_map_out<<<16, 256, 0, stream>>>(amacc, out1);

    // projection + residual
    gemm_bf16<4><<<dim3(8, 32), 256, 0, stream>>>(
        aob, projwb, proj_b, out0, xmix, nullptr, nullptr, wvec, MROWS, 1024, 1024);
}